// Round 8
// baseline (35.171 us; speedup 1.0000x reference)
//
#include <hip/hip_runtime.h>
#include <math.h>

#define FN 50
#define CARD 10000
#define NP 1225          // F*(F-1)/2
#define NPAD 1232
#define NJOBS 146        // 9 full 16-row tile-pairs + 2 rows of (3,3)
#define FSTRIDE 72       // halves per factor row (144 B)

typedef _Float16 half8 __attribute__((ext_vector_type(8)));
typedef __fp16 half2t __attribute__((ext_vector_type(2)));
typedef float floatx4 __attribute__((ext_vector_type(4)));

static __device__ __forceinline__ half2t h2max0(half2t v) {
  half2t r;
  r[0] = v[0] > (__fp16)0 ? v[0] : (__fp16)0;
  r[1] = v[1] > (__fp16)0 ? v[1] : (__fp16)0;
  return r;
}
static __device__ __forceinline__ float hdot2(half2t a, half2t b, float c) {
#if __has_builtin(__builtin_amdgcn_fdot2)
  return __builtin_amdgcn_fdot2(a, b, c, false);
#else
  return c + (float)a[0]*(float)b[0] + (float)a[1]*(float)b[1];
#endif
}

__global__ __launch_bounds__(256, 4)
void afm_kernel(const int* __restrict__ inp,
                const float* __restrict__ emb,
                const float* __restrict__ wlin,
                const float* __restrict__ blin,
                const float* __restrict__ W1,
                const float* __restrict__ b1,
                const float* __restrict__ W2,
                const float* __restrict__ b2,
                float* __restrict__ out)
{
  __shared__ __align__(16) _Float16 s_fac[FN][FSTRIDE];   // 7200 B
  __shared__ __align__(16) _Float16 s_w1t[64][64];        // 8192 B  W1^T: [a][d]
  __shared__ unsigned s_jobs[NJOBS + 2];                  // 592 B
  __shared__ __align__(8) __fp16 s_lg4[NPAD * 4];         // 9856 B per-kq logit partials
  __shared__ float s_pool[NPAD];                          // 4928 B
  __shared__ float s_logit[NPAD];                         // 4928 B
  __shared__ float s_wl[FN];
  __shared__ float s_red[16];

  const int tid  = threadIdx.x;
  const int b    = blockIdx.x;
  const int lane = tid & 63;
  const int wave = tid >> 6;
  const int c    = lane & 15;   // pair-column within tile
  const int kq   = lane >> 4;   // k-quarter 0..3

  // ---- phase 0a: job table. job = (i-row, 16-wide j-tile) ----
  // tile-pairs (I,J), I<=J over 4 i-tiles {0..15,16..31,32..47,48..49}:
  // tp 0..3 -> (0,0..3); tp 4..6 -> (1,1..3); tp 7..8 -> (2,2..3); then (3,3) rows
  if (tid < NJOBS) {
    int t = tid;
    int I, J, ii;
    if (t < 144) {
      int tp = t >> 4; ii = t & 15;
      I = (tp < 4) ? 0 : (tp < 7) ? 1 : 2;
      J = (tp < 4) ? tp : (tp < 7) ? (tp - 3) : (tp - 5);
    } else { I = 3; J = 3; ii = t - 144; }
    int i  = I * 16 + ii;
    int jb = J * 16;
    int pb1 = i * (99 - i) / 2 - i - 1 + jb + 1;   // pb+1 (pb can be -1)
    s_jobs[t] = (unsigned)i | ((unsigned)jb << 6) | ((unsigned)pb1 << 16);
  }

  // ---- phase 0b: factor gather f32 -> f16 LDS ----
  const int* inprow = inp + b * FN;
  for (int idx = tid; idx < FN * 16; idx += 256) {
    int f = idx >> 4, q = idx & 15;
    int flat = inprow[f] + f * CARD;
    floatx4 v = ((const floatx4*)emb)[(long)flat * 16 + q];
    _Float16* dst = &s_fac[f][q * 4];
    dst[0] = (_Float16)v[0]; dst[1] = (_Float16)v[1];
    dst[2] = (_Float16)v[2]; dst[3] = (_Float16)v[3];
  }
  if (tid < FN) {
    int flat = inprow[tid] + tid * CARD;
    s_wl[tid] = wlin[flat];
  }

  // ---- phase 0c: stage W1^T into LDS ([a][d], f16) ----
  {
    int d = tid >> 2, a0 = (tid & 3) * 16;
#pragma unroll
    for (int r = 0; r < 4; ++r) {
      floatx4 v = *(const floatx4*)&W1[d * 64 + a0 + r * 4];
      s_w1t[a0 + r * 4 + 0][d] = (_Float16)v[0];
      s_w1t[a0 + r * 4 + 1][d] = (_Float16)v[1];
      s_w1t[a0 + r * 4 + 2][d] = (_Float16)v[2];
      s_w1t[a0 + r * 4 + 3][d] = (_Float16)v[3];
    }
  }

  // bias (f32, MFMA C-init) and W2 (f16 packed) for this lane's a = mt*16+kq*4+r
  floatx4 bias[4];
  half2t w2h[4][2];
#pragma unroll
  for (int mt = 0; mt < 4; ++mt) {
    bias[mt] = ((const floatx4*)b1)[mt * 4 + kq];
    floatx4 wv = ((const floatx4*)W2)[mt * 4 + kq];
    w2h[mt][0] = __builtin_amdgcn_cvt_pkrtz(wv[0], wv[1]);
    w2h[mt][1] = __builtin_amdgcn_cvt_pkrtz(wv[2], wv[3]);
  }
  _Float16 onev = (c == 0) ? (_Float16)1 : (_Float16)0;
  half8 onesf = {onev, onev, onev, onev, onev, onev, onev, onev};

  __syncthreads();

  // ---- phase 0d: W1 fragments -> VGPRs from s_w1t (8 ds_read_b128, once) ----
  // w1f[ks][mt] = A[m=mt*16+c][k=ks*32+kq*8 .. +8]
  half8 w1f[2][4];
#pragma unroll
  for (int ks = 0; ks < 2; ++ks)
#pragma unroll
    for (int mt = 0; mt < 4; ++mt)
      w1f[ks][mt] = *(const half8*)&s_w1t[mt * 16 + c][ks * 32 + kq * 8];

  // ---- phase 1: job loop. job = (i, jb): pairs (i, jb..jb+15) ----
  const char* fbase = (const char*)&s_fac[0][0];
  const int koff = kq * 16;
  const floatx4 zf4 = {0.f, 0.f, 0.f, 0.f};

  int jt = wave;
  unsigned jw = s_jobs[jt];
  int ci = jw & 63, cjb = (int)((jw >> 6) & 63), cpb = (int)(jw >> 16) - 1;
  const char* fip = fbase + ci * (FSTRIDE * 2) + koff;
  half8 fi0 = *(const half8*)(fip);
  half8 fi1 = *(const half8*)(fip + 64);
  int prevJb = -1;
  half8 fj0, fj1;

  while (true) {
    if (cjb != prevJb) {                       // wave-uniform branch
      int jrow = cjb + c; if (jrow > FN - 1) jrow = FN - 1;
      const char* fjp = fbase + jrow * (FSTRIDE * 2) + koff;
      fj0 = *(const half8*)(fjp);
      fj1 = *(const half8*)(fjp + 64);
      prevJb = cjb;
    }
    // prefetch next job (word + f_i broadcast slices)
    int jn = jt + 4; if (jn > NJOBS - 1) jn = NJOBS - 1;
    unsigned jwn = s_jobs[jn];
    int ni = jwn & 63, njb = (int)((jwn >> 6) & 63), npb = (int)(jwn >> 16) - 1;
    const char* fnp = fbase + ni * (FSTRIDE * 2) + koff;
    half8 fin0 = *(const half8*)(fnp);
    half8 fin1 = *(const half8*)(fnp + 64);

    half8 pr0 = fi0 * fj0;                     // inter slices for 16 pairs
    half8 pr1 = fi1 * fj1;

    floatx4 acc[4];
#pragma unroll
    for (int mt = 0; mt < 4; ++mt)
      acc[mt] = __builtin_amdgcn_mfma_f32_16x16x32_f16(w1f[0][mt], pr0, bias[mt], 0, 0, 0);
#pragma unroll
    for (int mt = 0; mt < 4; ++mt)
      acc[mt] = __builtin_amdgcn_mfma_f32_16x16x32_f16(w1f[1][mt], pr1, acc[mt], 0, 0, 0);
    floatx4 ap = __builtin_amdgcn_mfma_f32_16x16x32_f16(onesf, pr0, zf4, 0, 0, 0);
    ap = __builtin_amdgcn_mfma_f32_16x16x32_f16(onesf, pr1, ap, 0, 0, 0);

    // epilogue: relu(h)+W2 dot (bias already in acc), per-kq partial
    float lg = 0.f;
#pragma unroll
    for (int mt = 0; mt < 4; ++mt) {
      half2t h0 = h2max0(__builtin_amdgcn_cvt_pkrtz(acc[mt][0], acc[mt][1]));
      half2t h1 = h2max0(__builtin_amdgcn_cvt_pkrtz(acc[mt][2], acc[mt][3]));
      lg = hdot2(h0, w2h[mt][0], lg);
      lg = hdot2(h1, w2h[mt][1], lg);
    }

    int j = cjb + c;
    bool valid = (j > ci) && (j < FN);
    if (valid) s_lg4[(cpb + c) * 4 + kq] = (__fp16)lg;
    if (valid && kq == 0) s_pool[cpb + c] = ap[0];  // D row 0 = pooled

    jt += 4;
    if (jt >= NJOBS) break;
    ci = ni; cjb = njb; cpb = npb;
    fi0 = fin0; fi1 = fin1;
  }

  __syncthreads();

  // ---- phase 2: sum kq partials, softmax, weighted pool, line_out ----
  float m = -1e30f;
  for (int p = tid; p < NP; p += 256) {
    const half2t* lp = (const half2t*)&s_lg4[p * 4];
    half2t sfh = lp[0] + lp[1];
    float lg = (float)sfh[0] + (float)sfh[1];
    s_logit[p] = lg;
    m = fmaxf(m, lg);
  }
#pragma unroll
  for (int o = 32; o; o >>= 1) m = fmaxf(m, __shfl_xor(m, o, 64));
  if (lane == 0) s_red[wave] = m;
  __syncthreads();
  m = fmaxf(fmaxf(s_red[0], s_red[1]), fmaxf(s_red[2], s_red[3]));
  float se = 0.f, spe = 0.f;
  for (int p = tid; p < NP; p += 256) {
    float e = __expf(s_logit[p] - m);
    se += e;
    spe += e * s_pool[p];
  }
#pragma unroll
  for (int o = 32; o; o >>= 1) {
    se  += __shfl_xor(se, o, 64);
    spe += __shfl_xor(spe, o, 64);
  }
  if (lane == 0) { s_red[4 + wave] = se; s_red[8 + wave] = spe; }
  __syncthreads();
  if (tid == 0) {
    float line = blin[0];
#pragma unroll
    for (int f = 0; f < FN; ++f) line += s_wl[f];
    float SE  = s_red[4] + s_red[5] + s_red[6]  + s_red[7];
    float SPE = s_red[8] + s_red[9] + s_red[10] + s_red[11];
    out[b] = line + SPE / SE;
  }
}

extern "C" void kernel_launch(void* const* d_in, const int* in_sizes, int n_in,
                              void* d_out, int out_size, void* d_ws, size_t ws_size,
                              hipStream_t stream) {
  const int*   inp  = (const int*)d_in[0];
  const float* emb  = (const float*)d_in[1];
  const float* wlin = (const float*)d_in[2];
  const float* blin = (const float*)d_in[3];
  const float* W1   = (const float*)d_in[4];
  const float* b1   = (const float*)d_in[5];
  const float* W2   = (const float*)d_in[6];
  const float* b2   = (const float*)d_in[7];
  float* outp = (float*)d_out;
  const int B = in_sizes[0] / FN;
  afm_kernel<<<B, 256, 0, stream>>>(inp, emb, wlin, blin, W1, b1, W2, b2, outp);
}